// Round 17
// baseline (470.561 us; speedup 1.0000x reference)
//
#include <hip/hip_runtime.h>
#include <hip/hip_bf16.h>

#define N_NODES 3072
#define S_SINK  256
#define DIN     64
#define NH      8

typedef __attribute__((ext_vector_type(8))) short short8v;
typedef __attribute__((ext_vector_type(4))) float f32x4;

#define LOG2E 1.4426950408889634f

#if defined(__has_builtin)
#if __has_builtin(__builtin_amdgcn_exp2f)
#define EXP2(x) __builtin_amdgcn_exp2f(x)
#else
#define EXP2(x) exp2f(x)
#endif
#else
#define EXP2(x) exp2f(x)
#endif

static __device__ __forceinline__ float gelu_exact(float v) {
    return 0.5f * v * (1.0f + erff(v * 0.70710678118654752f));
}
static __device__ __forceinline__ unsigned short f2b_rne(float f) {
    unsigned int b = __float_as_uint(f);
    b += 0x7fffu + ((b >> 16) & 1u);
    return (unsigned short)(b >> 16);
}
static __device__ __forceinline__ unsigned pack_b16(float a, float b) {
    unsigned r;
    asm("v_cvt_pk_bf16_f32 %0, %1, %2" : "=v"(r) : "v"(a), "v"(b));
    return r;
}
static __device__ __forceinline__ size_t bswz_idx(int m, int n) {
    int qt = m >> 4, cc = m & 15;
    int kt = n >> 4, gg = (n >> 2) & 3, rr = n & 3;
    return (((size_t)qt * 192 + kt) * 64 + gg * 16 + cc) * 4 + rr;
}
static __device__ __forceinline__ size_t kfrag_idx(int h, int k, int d) {
    return (((size_t)(h * 192 + (k >> 4)) * 64) + ((d >> 3) << 4) + (k & 15)) * 8 + (d & 7);
}
static __device__ __forceinline__ size_t vtfrag_idx(int h, int k, int d) {
    return ((((size_t)(h * 48 + (k >> 6)) * 2 + ((k >> 5) & 1)) * 2 + (d >> 4)) * 64
            + ((k >> 3) & 3) * 16 + (d & 15)) * 8 + (k & 7);
}

// ---------------- combined misc prep: weight cvt + maskadd + cn ----------------
struct CvtJobs {
    const float* src[9];
    unsigned short* dst[9];
    int cnt4[9];
};
__global__ __launch_bounds__(256) void prep_misc_kernel(CvtJobs cj, int total4, int ncvt,
                                                        const unsigned char* __restrict__ mask,
                                                        float* __restrict__ ma,
                                                        const float* __restrict__ C,
                                                        unsigned short* __restrict__ Cnb)
{
    int b = blockIdx.x;
    if (b < ncvt) {
        int i = b * 256 + threadIdx.x;
        if (i >= total4) return;
        int s = 0, base = 0;
        while (s < 9 && i >= base + cj.cnt4[s]) { base += cj.cnt4[s]; ++s; }
        int off = (i - base) * 4;
        float4 v = *(const float4*)(cj.src[s] + off);
        uint2 o;
        o.x = pack_b16(v.x, v.y);
        o.y = pack_b16(v.z, v.w);
        *(uint2*)(cj.dst[s] + off) = o;
        return;
    }
    b -= ncvt;
    if (b < 12) {
        int j = b * 256 + threadIdx.x;
        if (j < N_NODES) ma[j] = -10000.0f * LOG2E * (float)mask[j];
        return;
    }
    b -= 12;
    int w = threadIdx.x >> 6, lane = threadIdx.x & 63;
    int row = b * 4 + w;
    float4 v = *(const float4*)(C + (size_t)row * 256 + lane * 4);
    float s2 = v.x * v.x + v.y * v.y + v.z * v.z + v.w * v.w;
    #pragma unroll
    for (int o = 32; o > 0; o >>= 1) s2 += __shfl_xor(s2, o);
    float inv = 1.0f / (sqrtf(s2) + 1e-6f);
    uint2 o2;
    o2.x = pack_b16(v.x * inv, v.y * inv);
    o2.y = pack_b16(v.z * inv, v.w * inv);
    *(uint2*)(Cnb + (size_t)row * 256 + lane * 4) = o2;
}

// ---------------- node encode ----------------
__global__ __launch_bounds__(256) void node_encode_kernel(
    const float* __restrict__ x, const float* __restrict__ C,
    const unsigned char* __restrict__ mask,
    const float* __restrict__ Wp, const float* __restrict__ bp,
    const float* __restrict__ peW, const float* __restrict__ peb,
    const float* __restrict__ peg, const float* __restrict__ pebt,
    const float* __restrict__ gate,
    float* __restrict__ h, unsigned short* __restrict__ hb)
{
    int i = blockIdx.x, t = threadIdx.x;
    __shared__ float xs[DIN];
    __shared__ float r1[256], r2[256];
    __shared__ float zs[20];
    if (t < DIN) xs[t] = x[i * DIN + t];
    float c  = C[i * 256 + t];
    float cc = fminf(fmaxf(c, 0.0f), 1.0f);
    r1[t] = cc; r2[t] = cc * cc;
    __syncthreads();
    for (int s = 128; s > 0; s >>= 1) { if (t < s) { r1[t] += r1[t + s]; r2[t] += r2[t + s]; } __syncthreads(); }
    float cm  = r1[0] * (1.0f / 256.0f);
    float cms = r2[0] * (1.0f / 256.0f);
    __syncthreads();
    r1[t] = cc; r2[t] = cc;
    __syncthreads();
    for (int s = 128; s > 0; s >>= 1) { if (t < s) { r1[t] = fmaxf(r1[t], r1[t + s]); r2[t] = fminf(r2[t], r2[t + s]); } __syncthreads(); }
    float cmax = r1[0], cmin = r2[0];
    __syncthreads();
    if (t == 0) {
        float var  = fmaxf(cms - cm * cm, 0.0f);
        float cstd = sqrtf(var);
        zs[0] = cm; zs[1] = cmax; zs[2] = cmin; zs[3] = cstd;
        float w = 0.15f + 1e-6f;
        for (int k = 0; k < 8; ++k) {
            float ck = (float)k / 7.0f;
            float d1 = (cm   - ck) / w;
            float d2 = (cmax - ck) / w;
            zs[4 + k]  = expf(-0.5f * d1 * d1);
            zs[12 + k] = expf(-0.5f * d2 * d2);
        }
    }
    __syncthreads();
    float pl = peb[t];
    #pragma unroll
    for (int f = 0; f < 20; ++f) pl += zs[f] * peW[t * 20 + f];
    r1[t] = pl; r2[t] = pl * pl;
    __syncthreads();
    for (int s = 128; s > 0; s >>= 1) { if (t < s) { r1[t] += r1[t + s]; r2[t] += r2[t + s]; } __syncthreads(); }
    float m  = r1[0] * (1.0f / 256.0f);
    float vv = fmaxf(r2[0] * (1.0f / 256.0f) - m * m, 0.0f);
    float pe = (pl - m) * rsqrtf(vv + 1e-5f) * peg[t] + pebt[t];
    pe *= gate[0];
    if (mask[i] != 0) pe = 0.0f;
    float hv = bp[t];
    #pragma unroll
    for (int k = 0; k < DIN; ++k) hv += xs[k] * Wp[t * DIN + k];
    float o = hv + pe;
    h[(size_t)i * 256 + t] = o;
    hb[(size_t)i * 256 + t] = f2b_rne(o);
}

// ---------------- wave-per-row LN body ----------------
static __device__ __forceinline__ void ln_row(const float* in, const float* g, const float* b,
                                              unsigned short* out, int row, int lane) {
    float4 v = *(const float4*)(in + (size_t)row * 256 + lane * 4);
    float s  = v.x + v.y + v.z + v.w;
    float s2 = v.x * v.x + v.y * v.y + v.z * v.z + v.w * v.w;
    #pragma unroll
    for (int o = 32; o > 0; o >>= 1) { s += __shfl_xor(s, o); s2 += __shfl_xor(s2, o); }
    float m  = s * (1.0f / 256.0f);
    float vv = fmaxf(s2 * (1.0f / 256.0f) - m * m, 0.0f);
    float rs = rsqrtf(vv + 1e-5f);
    float4 gg = *(const float4*)(g + lane * 4);
    float4 bb = *(const float4*)(b + lane * 4);
    uint2 o2;
    o2.x = pack_b16((v.x - m) * rs * gg.x + bb.x, (v.y - m) * rs * gg.y + bb.y);
    o2.y = pack_b16((v.z - m) * rs * gg.z + bb.z, (v.w - m) * rs * gg.w + bb.w);
    *(uint2*)(out + (size_t)row * 256 + lane * 4) = o2;
}

__global__ __launch_bounds__(256) void ln_b16_w_kernel(const float* __restrict__ in, const float* __restrict__ g,
                                                       const float* __restrict__ b, unsigned short* __restrict__ out) {
    int w = threadIdx.x >> 6, lane = threadIdx.x & 63;
    ln_row(in, g, b, out, blockIdx.x * 4 + w, lane);
}

__global__ __launch_bounds__(256) void ln_dual_kernel(const float* __restrict__ in0, const float* __restrict__ g0,
                                                      const float* __restrict__ b0, unsigned short* __restrict__ out0, int n0,
                                                      const float* __restrict__ in1, const float* __restrict__ g1,
                                                      const float* __restrict__ b1, unsigned short* __restrict__ out1) {
    int w = threadIdx.x >> 6, lane = threadIdx.x & 63;
    int row = blockIdx.x * 4 + w;
    bool first = row < n0;
    const float* in = first ? in0 : in1;
    const float* g  = first ? g0  : g1;
    const float* b  = first ? b0  : b1;
    unsigned short* out = first ? out0 : out1;
    ln_row(in, g, b, out, first ? row : row - n0, lane);
}

__global__ __launch_bounds__(256) void ln_out_w_kernel(const float* __restrict__ in, const float* __restrict__ g,
                                                       const float* __restrict__ b, float* __restrict__ out) {
    int w = threadIdx.x >> 6, lane = threadIdx.x & 63;
    int row = blockIdx.x * 4 + w;
    float4 v = *(const float4*)(in + (size_t)row * 256 + lane * 4);
    float s  = v.x + v.y + v.z + v.w;
    float s2 = v.x * v.x + v.y * v.y + v.z * v.z + v.w * v.w;
    #pragma unroll
    for (int o = 32; o > 0; o >>= 1) { s += __shfl_xor(s, o); s2 += __shfl_xor(s2, o); }
    float m  = s * (1.0f / 256.0f);
    float vv = fmaxf(s2 * (1.0f / 256.0f) - m * m, 0.0f);
    float rs = rsqrtf(vv + 1e-5f);
    float4 gg = *(const float4*)(g + lane * 4);
    float4 bb = *(const float4*)(b + lane * 4);
    float4 o4;
    o4.x = (v.x - m) * rs * gg.x + bb.x;
    o4.y = (v.y - m) * rs * gg.y + bb.y;
    o4.z = (v.z - m) * rs * gg.z + bb.z;
    o4.w = (v.w - m) * rs * gg.w + bb.w;
    *(float4*)(out + (size_t)row * 256 + lane * 4) = o4;
}

// ---------------- multi-job MFMA GEMM (128x64 tile, MF=4) ----------------
struct GJob {
    const unsigned short* A; const int* ridx; const unsigned short* W;
    const float* bias; const float* res; const float* scale;
    void* out; void* out2; void* vtf;
    int lda, ldw, ldo, omode, kbase, K, act, gx;
    float scmul;
};

template<int MF>
static __device__ __forceinline__ void gemm_body(const GJob& j, int bx, int by) {
    constexpr int BM = MF * 32;
    __shared__ unsigned short As[BM][72];
    __shared__ unsigned short Ws[64][72];
    int tid = threadIdx.x;
    int lane = tid & 63, wid = tid >> 6;
    int c15 = lane & 15, g = lane >> 4;
    int wm = wid & 1, wn = wid >> 1;
    int row0 = by * BM, col0 = bx * 64;
    f32x4 acc[MF][2];
    const f32x4 zf = {0.f, 0.f, 0.f, 0.f};
    #pragma unroll
    for (int i = 0; i < MF; ++i) { acc[i][0] = zf; acc[i][1] = zf; }

    for (int k0 = 0; k0 < j.K; k0 += 64) {
        #pragma unroll
        for (int hh = 0; hh < MF; ++hh) {
            int cid = tid + hh * 256;
            int rr = cid >> 3, cc = (cid & 7) * 8;
            int arow = j.ridx ? j.ridx[row0 + rr] : (row0 + rr);
            *(short8v*)(&As[rr][cc]) = *(const short8v*)(j.A + (size_t)arow * j.lda + k0 + cc);
        }
        #pragma unroll
        for (int hh = 0; hh < 2; ++hh) {
            int cid = tid + hh * 256;
            int rr = cid >> 3, cc = (cid & 7) * 8;
            *(short8v*)(&Ws[rr][cc]) = *(const short8v*)(j.W + (size_t)(col0 + rr) * j.ldw + k0 + cc);
        }
        __syncthreads();
        #pragma unroll
        for (int ks = 0; ks < 2; ++ks) {
            short8v a[MF], w0, w1;
            #pragma unroll
            for (int mf = 0; mf < MF; ++mf)
                a[mf] = *(const short8v*)(&As[wm * (BM / 2) + mf * 16 + c15][ks * 32 + g * 8]);
            w0 = *(const short8v*)(&Ws[wn * 32 + c15][ks * 32 + g * 8]);
            w1 = *(const short8v*)(&Ws[wn * 32 + 16 + c15][ks * 32 + g * 8]);
            #pragma unroll
            for (int mf = 0; mf < MF; ++mf) {
                acc[mf][0] = __builtin_amdgcn_mfma_f32_16x16x32_bf16(a[mf], w0, acc[mf][0], 0, 0, 0);
                acc[mf][1] = __builtin_amdgcn_mfma_f32_16x16x32_bf16(a[mf], w1, acc[mf][1], 0, 0, 0);
            }
        }
        __syncthreads();
    }
    float sc = (j.scale ? *j.scale : 1.0f) * j.scmul;
    #pragma unroll
    for (int nf = 0; nf < 2; ++nf) {
        int n = col0 + wn * 32 + nf * 16 + c15;
        float bv = j.bias ? j.bias[n] : 0.0f;
        #pragma unroll
        for (int mf = 0; mf < MF; ++mf) {
            #pragma unroll
            for (int r = 0; r < 4; ++r) {
                int m = row0 + wm * (BM / 2) + mf * 16 + g * 4 + r;
                float v = acc[mf][nf][r] * sc + bv;
                if (j.act) v = gelu_exact(v);
                if (j.res) v += j.res[(size_t)m * j.ldo + n];
                if (j.omode == 0) {
                    ((float*)j.out)[(size_t)m * j.ldo + n] = v;
                    if (j.out2) ((unsigned short*)j.out2)[(size_t)m * j.ldo + n] = f2b_rne(v);
                } else if (j.omode == 1) {
                    ((unsigned short*)j.out)[(size_t)m * j.ldo + n] = f2b_rne(v);
                } else if (j.omode == 2) {
                    ((unsigned short*)j.out)[bswz_idx(m, n)] = f2b_rne(v);
                } else {
                    unsigned short bw = f2b_rne(v);
                    int nk = n - j.kbase;
                    if (nk < 0) {
                        ((unsigned short*)j.out)[(size_t)m * j.ldo + n] = bw;
                    } else if (nk < 256) {
                        ((unsigned short*)j.out2)[kfrag_idx(nk >> 5, m, nk & 31)] = bw;
                    } else {
                        ((unsigned short*)j.vtf)[vtfrag_idx((nk - 256) >> 5, m, (nk - 256) & 31)] = bw;
                    }
                }
            }
        }
    }
}

__global__ __launch_bounds__(256) void gemm_multi_kernel(GJob j0, GJob j1, GJob j2, int e0, int e1) {
    int b = blockIdx.x;
    GJob j;
    int bb;
    if (b < e0)      { j = j0; bb = b; }
    else if (b < e1) { j = j1; bb = b - e0; }
    else             { j = j2; bb = b - e1; }
    gemm_body<4>(j, bb % j.gx, bb / j.gx);
}

// ---------------- transpose-swz body ----------------
static __device__ __forceinline__ void transpose_body(const float* C, const float* beta,
                                                      const float* maskadd, unsigned short* CTswz,
                                                      int bxi, int byi) {
    __shared__ float tile[32][33];
    int bx = bxi * 32;
    int by = byi * 32;
    int tx = threadIdx.x & 31, ty = threadIdx.x >> 5;
    float bt = beta[0] * LOG2E;
    #pragma unroll
    for (int r = 0; r < 4; ++r) {
        int row = bx + ty + r * 8;
        tile[ty + r * 8][tx] = C[(size_t)row * 256 + by + tx];
    }
    __syncthreads();
    #pragma unroll
    for (int r = 0; r < 4; ++r) {
        int srow = by + ty + r * 8;
        int col  = bx + tx;
        CTswz[bswz_idx(srow, col)] = f2b_rne(bt * tile[tx][ty + r * 8] + maskadd[col]);
    }
}

__global__ __launch_bounds__(256) void mega0_kernel(
    const float* __restrict__ C, const float* __restrict__ beta,
    const float* __restrict__ maskadd, unsigned short* __restrict__ CTswz,
    GJob j0, GJob j1, int ntr, int e0)
{
    int b = blockIdx.x;
    if (b < ntr) { transpose_body(C, beta, maskadd, CTswz, b % 96, b / 96); return; }
    b -= ntr;
    GJob j;
    int bb;
    if (b < e0) { j = j0; bb = b; }
    else        { j = j1; bb = b - e0; }
    gemm_body<4>(j, bb % j.gx, bb / j.gx);
}

// ---------------- split-K MFMA flash attention (body) ----------------
template<int SPLIT>
static __device__ __forceinline__ void attn_body(
    const unsigned short* __restrict__ Qb, int ldq,
    const unsigned short* __restrict__ Kfrag,
    const unsigned short* __restrict__ VTfrag,
    const unsigned short* __restrict__ biasswz,
    unsigned short* __restrict__ out, int qx)
{
    constexpr int KT = 48 / SPLIT;
    __shared__ unsigned short P_all[SPLIT * 32 * 72];
    __shared__ float ml[SPLIT * 64];
    const int head = blockIdx.y;
    const int i0 = qx * 32;
    const int qt0 = qx * 2;
    const int tid = threadIdx.x;
    const int lane = tid & 63, w = tid >> 6;
    const int c15 = lane & 15, g = lane >> 4;
    unsigned short* P_lds = P_all + w * (32 * 72);
    const unsigned short* Kf  = Kfrag  + (size_t)head * 192 * 512;
    const unsigned short* VTf = VTfrag + (size_t)head * 48 * 2048;
    const f32x4 zf = {0.f, 0.f, 0.f, 0.f};
    const float rsl2 = 0.25503164113124427f;

    short8v qf[2];
    #pragma unroll
    for (int nf = 0; nf < 2; ++nf)
        qf[nf] = *(const short8v*)(Qb + (size_t)(i0 + nf * 16 + c15) * ldq + head * 32 + g * 8);

    float m_[2] = {-1e30f, -1e30f};
    float l_[2] = {0.f, 0.f};
    f32x4 acc[2][2];
    acc[0][0] = zf; acc[0][1] = zf; acc[1][0] = zf; acc[1][1] = zf;

    for (int kt = 0; kt < KT; ++kt) {
        const int k0 = (w * KT + kt) * 64;
        const int kt16 = k0 >> 4;
        short8v kf[4];
        #pragma unroll
        for (int mf = 0; mf < 4; ++mf)
            kf[mf] = *(const short8v*)(Kf + ((size_t)(kt16 + mf) * 64 + lane) * 8);
        f32x4 s[4][2];
        __builtin_amdgcn_s_setprio(1);
        #pragma unroll
        for (int mf = 0; mf < 4; ++mf)
            #pragma unroll
            for (int nf = 0; nf < 2; ++nf)
                s[mf][nf] = __builtin_amdgcn_mfma_f32_16x16x32_bf16(kf[mf], qf[nf], zf, 0, 0, 0);
        __builtin_amdgcn_s_setprio(0);
        #pragma unroll
        for (int nf = 0; nf < 2; ++nf) {
            const unsigned short* bb = biasswz + ((size_t)(qt0 + nf) * 192 + kt16) * 256 + lane * 4;
            #pragma unroll
            for (int mf = 0; mf < 4; ++mf) {
                uint2 bv = *(const uint2*)(bb + mf * 256);
                s[mf][nf][0] = s[mf][nf][0] * rsl2 + __uint_as_float(bv.x << 16);
                s[mf][nf][1] = s[mf][nf][1] * rsl2 + __uint_as_float(bv.x & 0xffff0000u);
                s[mf][nf][2] = s[mf][nf][2] * rsl2 + __uint_as_float(bv.y << 16);
                s[mf][nf][3] = s[mf][nf][3] * rsl2 + __uint_as_float(bv.y & 0xffff0000u);
            }
        }
        #pragma unroll
        for (int nf = 0; nf < 2; ++nf) {
            float t0 = fmaxf(fmaxf(s[0][nf][0], s[0][nf][1]), fmaxf(s[0][nf][2], s[0][nf][3]));
            float t1 = fmaxf(fmaxf(s[1][nf][0], s[1][nf][1]), fmaxf(s[1][nf][2], s[1][nf][3]));
            float t2 = fmaxf(fmaxf(s[2][nf][0], s[2][nf][1]), fmaxf(s[2][nf][2], s[2][nf][3]));
            float t3 = fmaxf(fmaxf(s[3][nf][0], s[3][nf][1]), fmaxf(s[3][nf][2], s[3][nf][3]));
            float tmax = fmaxf(fmaxf(t0, t1), fmaxf(t2, t3));
            tmax = fmaxf(tmax, __shfl_xor(tmax, 16));
            tmax = fmaxf(tmax, __shfl_xor(tmax, 32));
            if (!__all(tmax <= m_[nf] + 8.0f)) {
                float mn = fmaxf(m_[nf], tmax);
                float scl = EXP2(m_[nf] - mn);
                m_[nf] = mn;
                l_[nf] *= scl;
                #pragma unroll
                for (int mf = 0; mf < 2; ++mf) {
                    acc[mf][nf][0] *= scl; acc[mf][nf][1] *= scl;
                    acc[mf][nf][2] *= scl; acc[mf][nf][3] *= scl;
                }
            }
            float mcur = m_[nf];
            float ps0 = 0.f, ps1 = 0.f, ps2 = 0.f, ps3 = 0.f;
            #pragma unroll
            for (int mf = 0; mf < 4; ++mf) {
                float p0 = EXP2(s[mf][nf][0] - mcur);
                float p1 = EXP2(s[mf][nf][1] - mcur);
                float p2 = EXP2(s[mf][nf][2] - mcur);
                float p3 = EXP2(s[mf][nf][3] - mcur);
                s[mf][nf][0] = p0; s[mf][nf][1] = p1;
                s[mf][nf][2] = p2; s[mf][nf][3] = p3;
                ps0 += p0; ps1 += p1; ps2 += p2; ps3 += p3;
            }
            l_[nf] += (ps0 + ps1) + (ps2 + ps3);
            const int q = nf * 16 + c15;
            #pragma unroll
            for (int mf = 0; mf < 4; ++mf) {
                uint2 pv;
                pv.x = pack_b16(s[mf][nf][0], s[mf][nf][1]);
                pv.y = pack_b16(s[mf][nf][2], s[mf][nf][3]);
                *(uint2*)(P_lds + q * 72 + mf * 16 + g * 4) = pv;
            }
        }
        const unsigned short* vb = VTf + (size_t)(k0 >> 6) * 2048;
        #pragma unroll
        for (int ks = 0; ks < 2; ++ks) {
            short8v pB[2], vA[2];
            #pragma unroll
            for (int nf = 0; nf < 2; ++nf)
                pB[nf] = *(const short8v*)(P_lds + (nf * 16 + c15) * 72 + ks * 32 + g * 8);
            #pragma unroll
            for (int mf = 0; mf < 2; ++mf)
                vA[mf] = *(const short8v*)(vb + ((size_t)(ks * 2 + mf) * 64 + lane) * 8);
            __builtin_amdgcn_s_setprio(1);
            #pragma unroll
            for (int mf = 0; mf < 2; ++mf)
                #pragma unroll
                for (int nf = 0; nf < 2; ++nf)
                    acc[mf][nf] = __builtin_amdgcn_mfma_f32_16x16x32_bf16(vA[mf], pB[nf], acc[mf][nf], 0, 0, 0);
            __builtin_amdgcn_s_setprio(0);
        }
    }

    float* Olds = (float*)P_all;
    #pragma unroll
    for (int nf = 0; nf < 2; ++nf) {
        float lv = l_[nf];
        lv += __shfl_xor(lv, 16);
        lv += __shfl_xor(lv, 32);
        int q = nf * 16 + c15;
        #pragma unroll
        for (int mf = 0; mf < 2; ++mf)
            *(f32x4*)(Olds + w * 1152 + q * 36 + mf * 16 + g * 4) = acc[mf][nf];
        if (g == 0) {
            ml[w * 64 + q] = m_[nf];
            ml[w * 64 + 32 + q] = lv;
        }
    }
    __syncthreads();
    if (tid < 256) {
        int q = tid >> 3, d0 = (tid & 7) * 4;
        float M = -1e30f;
        #pragma unroll
        for (int s = 0; s < SPLIT; ++s) M = fmaxf(M, ml[s * 64 + q]);
        float L = 0.f;
        float v0 = 0, v1 = 0, v2 = 0, v3 = 0;
        #pragma unroll
        for (int s = 0; s < SPLIT; ++s) {
            float wv = EXP2(ml[s * 64 + q] - M);
            L += wv * ml[s * 64 + 32 + q];
            const float* op = Olds + s * 1152 + q * 36 + d0;
            v0 += wv * op[0]; v1 += wv * op[1];
            v2 += wv * op[2]; v3 += wv * op[3];
        }
        float invL = 1.0f / L;
        uint2 pk;
        pk.x = pack_b16(v0 * invL, v1 * invL);
        pk.y = pack_b16(v2 * invL, v3 * invL);
        *(uint2*)(out + (size_t)(i0 + q) * 256 + head * 32 + d0) = pk;
    }
}

template<int SPLIT>
__global__ __launch_bounds__(64 * SPLIT) void attn_multi_kernel(
    const unsigned short* Q0, const unsigned short* K0, const unsigned short* V0,
    const unsigned short* B0, unsigned short* O0, int nx0,
    const unsigned short* Q1, const unsigned short* K1, const unsigned short* V1,
    const unsigned short* B1, unsigned short* O1)
{
    int bx = blockIdx.x;
    bool first = bx < nx0;
    const unsigned short* Q = first ? Q0 : Q1;
    const unsigned short* K = first ? K0 : K1;
    const unsigned short* V = first ? V0 : V1;
    const unsigned short* B = first ? B0 : B1;
    unsigned short* O = first ? O0 : O1;
    attn_body<SPLIT>(Q, 256, K, V, B, O, first ? bx : bx - nx0);
}

extern "C" void kernel_launch(void* const* d_in, const int* in_sizes, int n_in,
                              void* d_out, int out_size, void* d_ws, size_t ws_size,
                              hipStream_t stream)
{
    const float* x        = (const float*)d_in[0];
    const float* C        = (const float*)d_in[1];
    const int*   sidx     = (const int*)d_in[2];
    const unsigned char* mask = (const unsigned char*)d_in[3];
    const float* proj_W   = (const float*)d_in[4];
    const float* proj_b   = (const float*)d_in[5];
    const float* peW      = (const float*)d_in[6];
    const float* peb      = (const float*)d_in[7];
    const float* peg      = (const float*)d_in[8];
    const float* pebt     = (const float*)d_in[9];
    const float* pe_gate  = (const float*)d_in[10];
    const float* alpha_nn = (const float*)d_in[11];
    const float* beta_sn  = (const float*)d_in[12];
    const float* sqW      = (const float*)d_in[13];
    const float* sqb      = (const float*)d_in[14];
    const float* sn_Win   = (const float*)d_in[15];
    const float* sn_bin   = (const float*)d_in[16];
    const float* sn_Wout  = (const float*)d_in[17];
    const float* sn_bout  = (const float*)d_in[18];
    const float* nn_Win   = (const float*)d_in[19];
    const float* nn_bin   = (const float*)d_in[20];
    const float* nn_Wout  = (const float*)d_in[21];
    const float* nn_bout  = (const float*)d_in[22];
    const float* ln_s_g   = (const float*)d_in[23];
    const float* ln_s_b   = (const float*)d_in[24];
    const float* ln_n1_g  = (const float*)d_in[25];
    const float* ln_n1_b  = (const float*)d_in[26];
    const float* ln_n2_g  = (const float*)d_in[27];
    const float* ln_n2_b  = (const float*)d_in[28];
    const float* ffn_W1   = (const float*)d_in[29];
    const float* ffn_b1   = (const float*)d_in[30];
    const float* ffn_W2   = (const float*)d_in[31];
    const float* ffn_b2   = (const float*)d_in[32];
    const float* ffs_W1   = (const float*)d_in[33];
    const float* ffs_b1   = (const float*)d_in[34];
    const float* ffs_W2   = (const float*)d_in[35];
    const float* ffs_b2   = (const float*)d_in[36];
    const float* ln_og    = (const float*)d_in[37];
    const float* ln_ob    = (const float*)d_in[38];

    float* ws = (float*)d_ws;
    float* h       = ws;                                          // 786432 f
    float* sinkq   = ws + 786432;                                 // 65536
    float* maskadd = ws + 851968;                                 // 4096
    unsigned short* Cnb     = (unsigned short*)(ws + 856064);     // 393216 f
    unsigned short* hb      = (unsigned short*)(ws + 1249280);    // 393216 f
    unsigned short* hnb     = (unsigned short*)(ws + 1642496);    // 393216 f
    unsigned short* attnob_n= (unsigned short*)(ws + 2035712);    // 393216 f
    unsigned short* attnob_s= (unsigned short*)(ws + 2428928);    // 32768 f
    unsigned short* sqnb    = (unsigned short*)(ws + 2461696);    // 32768 f
    unsigned short* sinkqb  = (unsigned short*)(ws + 2494464);    // 32768 f
    unsigned short* Kfrag_n = (unsigned short*)(ws + 2527232);    // 393216 f
    unsigned short* VTfrag_n= (unsigned short*)(ws + 2920448);    // 393216 f
    unsigned short* Kfrag_s = (unsigned short*)(ws + 3313664);    // 393216 f
    unsigned short* VTfrag_s= (unsigned short*)(ws + 3706880);    // 393216 f
    unsigned short* CTswz   = (unsigned short*)(ws + 4100096);    // 393216 f
    unsigned short* biasswz = (unsigned short*)(ws + 4493312);    // 4718592 f
    unsigned short* wb      = (unsigned short*)(ws + 9211904);    // 2392064 f
    float* big      = ws + 11603968;                              // 1966080 f -> ends 13570048
    unsigned short* sqWb    = wb;
    unsigned short* snWinb  = wb + 65536;
    unsigned short* snWoutb = wb + 655360;
    unsigned short* nnWinb  = wb + 851968;
    unsigned short* nnWoutb = wb + 1441792;
    unsigned short* ffnW1b  = wb + 1638400;
    unsigned short* ffnW2b  = wb + 2424832;
    unsigned short* ffsW1b  = wb + 3211264;
    unsigned short* ffsW2b  = wb + 3997696;
    unsigned short* q_sb  = (unsigned short*)big;                 // 256x256
    unsigned short* mid_sb= (unsigned short*)big + 65536;         // 256x1024
    unsigned short* Qnb   = (unsigned short*)big + 327680;        // 3072x256
    unsigned short* midb  = (unsigned short*)big + 1114112;       // 3072x1024

    dim3 b256(256), b512(512);
    GJob jz = {};  jz.gx = 1;

    CvtJobs cj;
    cj.src[0] = sqW;     cj.dst[0] = sqWb;    cj.cnt4[0] = 16384;
    cj.src[1] = sn_Win;  cj.dst[1] = snWinb;  cj.cnt4[1] = 147456;
    cj.src[2] = sn_Wout; cj.dst[2] = snWoutb; cj.cnt4[2] = 49152;
    cj.src[3] = nn_Win;  cj.dst[3] = nnWinb;  cj.cnt4[3] = 147456;
    cj.src[4] = nn_Wout; cj.dst[4] = nnWoutb; cj.cnt4[4] = 49152;
    cj.src[5] = ffn_W1;  cj.dst[5] = ffnW1b;  cj.cnt4[5] = 196608;
    cj.src[6] = ffn_W2;  cj.dst[6] = ffnW2b;  cj.cnt4[6] = 196608;
    cj.src[7] = ffs_W1;  cj.dst[7] = ffsW1b;  cj.cnt4[7] = 196608;
    cj.src[8] = ffs_W2;  cj.dst[8] = ffsW2b;  cj.cnt4[8] = 196608;

    prep_misc_kernel<<<4672 + 12 + 768, b256, 0, stream>>>(cj, 1196032, 4672, mask, maskadd, C, Cnb);
    node_encode_kernel<<<N_NODES, b256, 0, stream>>>(x, C, mask, proj_W, proj_b, peW, peb, peg, pebt, pe_gate, h, hb);
    {   // CT transpose-swz + sink q proj (gathered, M=256: 2x4=8 blocks) + biasnn (M=3072: 24x48=1152)
        GJob j0 = {hb, sidx, sqWb, sqb, nullptr, nullptr, sinkq, nullptr, nullptr, 256, 256, 256, 0, 0, 256, 0, 4, 1.0f};
        GJob j1 = {Cnb, nullptr, Cnb, maskadd, nullptr, alpha_nn, biasswz, nullptr, nullptr, 256, 256, 3072, 2, 0, 256, 0, 48, LOG2E};
        mega0_kernel<<<768 + 8 + 1152, b256, 0, stream>>>(C, beta_sn, maskadd, CTswz, j0, j1, 768, 8);
    }

    for (int l = 0; l < 3; ++l) {
        const float* lsg = ln_s_g + l * 256,  *lsb = ln_s_b + l * 256;
        const float* l1g = ln_n1_g + l * 256, *l1b = ln_n1_b + l * 256;
        ln_dual_kernel<<<832, b256, 0, stream>>>(sinkq, lsg, lsb, sqnb, 256, h, l1g, l1b, hnb);
        {   // q_s proj (8) + sink KV->frag (24x8=192) + node QKV->frag (24x12=288)
            GJob j0 = {sqnb, nullptr, snWinb + (size_t)l * 196608, sn_bin + l * 768, nullptr, nullptr, q_sb, nullptr, nullptr, 256, 256, 256, 1, 0, 256, 0, 4, 1.0f};
            GJob j1 = {hb, nullptr, snWinb + (size_t)l * 196608 + 65536, sn_bin + l * 768 + 256, nullptr, nullptr, nullptr, Kfrag_s, VTfrag_s, 256, 256, 0, 3, 0, 256, 0, 8, 1.0f};
            GJob j2 = {hnb, nullptr, nnWinb + (size_t)l * 196608, nn_bin + l * 768, nullptr, nullptr, Qnb, Kfrag_n, VTfrag_n, 256, 256, 256, 3, 256, 256, 0, 12, 1.0f};
            gemm_multi_kernel<<<8 + 192 + 288, b256, 0, stream>>>(j0, j1, j2, 8, 8 + 192);
        }
        attn_multi_kernel<8><<<dim3(8 + 96, 8), b512, 0, stream>>>(
            q_sb, Kfrag_s, VTfrag_s, CTswz, attnob_s, 8,
            Qnb, Kfrag_n, VTfrag_n, biasswz, attnob_n);
        {   // wout_s (8) + wout_n (24x4=96)
            GJob j0 = {attnob_s, nullptr, snWoutb + (size_t)l * 65536, sn_bout + l * 256, sinkq, nullptr, sinkq, sinkqb, nullptr, 256, 256, 256, 0, 0, 256, 0, 4, 1.0f};
            GJob j1 = {attnob_n, nullptr, nnWoutb + (size_t)l * 65536, nn_bout + l * 256, h, nullptr, h, nullptr, nullptr, 256, 256, 256, 0, 0, 256, 0, 4, 1.0f};
            gemm_multi_kernel<<<8 + 96, b256, 0, stream>>>(j0, j1, jz, 8, 8 + 96);
        }
        ln_b16_w_kernel<<<768, b256, 0, stream>>>(h, ln_n2_g + l * 256, ln_n2_b + l * 256, hnb);
        {   // ffs1 (2x16=32) + ffn1 (24x16=384), GELU
            GJob j0 = {sinkqb, nullptr, ffsW1b + (size_t)l * 262144, ffs_b1 + l * 1024, nullptr, nullptr, mid_sb, nullptr, nullptr, 256, 256, 1024, 1, 0, 256, 1, 16, 1.0f};
            GJob j1 = {hnb, nullptr, ffnW1b + (size_t)l * 262144, ffn_b1 + l * 1024, nullptr, nullptr, midb, nullptr, nullptr, 256, 256, 1024, 1, 0, 256, 1, 16, 1.0f};
            gemm_multi_kernel<<<32 + 384, b256, 0, stream>>>(j0, j1, jz, 32, 32 + 384);
        }
        {   // ffs2 (8) + ffn2 (96)
            GJob j0 = {mid_sb, nullptr, ffsW2b + (size_t)l * 262144, ffs_b2 + l * 256, sinkq, nullptr, sinkq, nullptr, nullptr, 1024, 1024, 256, 0, 0, 1024, 0, 4, 1.0f};
            GJob j1 = {midb, nullptr, ffnW2b + (size_t)l * 262144, ffn_b2 + l * 256, h, nullptr, h, hb, nullptr, 1024, 1024, 256, 0, 0, 1024, 0, 4, 1.0f};
            gemm_multi_kernel<<<8 + 96, b256, 0, stream>>>(j0, j1, jz, 8, 8 + 96);
        }
    }

    ln_out_w_kernel<<<64, b256, 0, stream>>>(sinkq, ln_og, ln_ob, (float*)d_out);
}

// Round 18
// 340.716 us; speedup vs baseline: 1.3811x; 1.3811x over previous
//
#include <hip/hip_runtime.h>
#include <hip/hip_bf16.h>

#define N_NODES 3072
#define S_SINK  256
#define DIN     64
#define NH      8

typedef __attribute__((ext_vector_type(8))) short short8v;
typedef __attribute__((ext_vector_type(4))) float f32x4;

#define LOG2E 1.4426950408889634f

#if defined(__has_builtin)
#if __has_builtin(__builtin_amdgcn_exp2f)
#define EXP2(x) __builtin_amdgcn_exp2f(x)
#else
#define EXP2(x) exp2f(x)
#endif
#else
#define EXP2(x) exp2f(x)
#endif

static __device__ __forceinline__ float gelu_exact(float v) {
    return 0.5f * v * (1.0f + erff(v * 0.70710678118654752f));
}
static __device__ __forceinline__ unsigned short f2b_rne(float f) {
    unsigned int b = __float_as_uint(f);
    b += 0x7fffu + ((b >> 16) & 1u);
    return (unsigned short)(b >> 16);
}
static __device__ __forceinline__ unsigned pack_b16(float a, float b) {
    unsigned r;
    asm("v_cvt_pk_bf16_f32 %0, %1, %2" : "=v"(r) : "v"(a), "v"(b));
    return r;
}
static __device__ __forceinline__ size_t bswz_idx(int m, int n) {
    int qt = m >> 4, cc = m & 15;
    int kt = n >> 4, gg = (n >> 2) & 3, rr = n & 3;
    return (((size_t)qt * 192 + kt) * 64 + gg * 16 + cc) * 4 + rr;
}
static __device__ __forceinline__ size_t kfrag_idx(int h, int k, int d) {
    return (((size_t)(h * 192 + (k >> 4)) * 64) + ((d >> 3) << 4) + (k & 15)) * 8 + (d & 7);
}
static __device__ __forceinline__ size_t vtfrag_idx(int h, int k, int d) {
    return ((((size_t)(h * 48 + (k >> 6)) * 2 + ((k >> 5) & 1)) * 2 + (d >> 4)) * 64
            + ((k >> 3) & 3) * 16 + (d & 15)) * 8 + (k & 7);
}

// ---------------- combined misc prep: weight cvt + maskadd + cn ----------------
struct CvtJobs {
    const float* src[9];
    unsigned short* dst[9];
    int cnt4[9];
};
__global__ __launch_bounds__(256) void prep_misc_kernel(CvtJobs cj, int total4, int ncvt,
                                                        const unsigned char* __restrict__ mask,
                                                        float* __restrict__ ma,
                                                        const float* __restrict__ C,
                                                        unsigned short* __restrict__ Cnb)
{
    int b = blockIdx.x;
    if (b < ncvt) {
        int i = b * 256 + threadIdx.x;
        if (i >= total4) return;
        int s = 0, base = 0;
        while (s < 9 && i >= base + cj.cnt4[s]) { base += cj.cnt4[s]; ++s; }
        int off = (i - base) * 4;
        float4 v = *(const float4*)(cj.src[s] + off);
        uint2 o;
        o.x = pack_b16(v.x, v.y);
        o.y = pack_b16(v.z, v.w);
        *(uint2*)(cj.dst[s] + off) = o;
        return;
    }
    b -= ncvt;
    if (b < 12) {
        int j = b * 256 + threadIdx.x;
        if (j < N_NODES) ma[j] = -10000.0f * LOG2E * (float)mask[j];
        return;
    }
    b -= 12;
    int w = threadIdx.x >> 6, lane = threadIdx.x & 63;
    int row = b * 4 + w;
    float4 v = *(const float4*)(C + (size_t)row * 256 + lane * 4);
    float s2 = v.x * v.x + v.y * v.y + v.z * v.z + v.w * v.w;
    #pragma unroll
    for (int o = 32; o > 0; o >>= 1) s2 += __shfl_xor(s2, o);
    float inv = 1.0f / (sqrtf(s2) + 1e-6f);
    uint2 o2;
    o2.x = pack_b16(v.x * inv, v.y * inv);
    o2.y = pack_b16(v.z * inv, v.w * inv);
    *(uint2*)(Cnb + (size_t)row * 256 + lane * 4) = o2;
}

// ---------------- node encode ----------------
__global__ __launch_bounds__(256) void node_encode_kernel(
    const float* __restrict__ x, const float* __restrict__ C,
    const unsigned char* __restrict__ mask,
    const float* __restrict__ Wp, const float* __restrict__ bp,
    const float* __restrict__ peW, const float* __restrict__ peb,
    const float* __restrict__ peg, const float* __restrict__ pebt,
    const float* __restrict__ gate,
    float* __restrict__ h, unsigned short* __restrict__ hb)
{
    int i = blockIdx.x, t = threadIdx.x;
    __shared__ float xs[DIN];
    __shared__ float r1[256], r2[256];
    __shared__ float zs[20];
    if (t < DIN) xs[t] = x[i * DIN + t];
    float c  = C[i * 256 + t];
    float cc = fminf(fmaxf(c, 0.0f), 1.0f);
    r1[t] = cc; r2[t] = cc * cc;
    __syncthreads();
    for (int s = 128; s > 0; s >>= 1) { if (t < s) { r1[t] += r1[t + s]; r2[t] += r2[t + s]; } __syncthreads(); }
    float cm  = r1[0] * (1.0f / 256.0f);
    float cms = r2[0] * (1.0f / 256.0f);
    __syncthreads();
    r1[t] = cc; r2[t] = cc;
    __syncthreads();
    for (int s = 128; s > 0; s >>= 1) { if (t < s) { r1[t] = fmaxf(r1[t], r1[t + s]); r2[t] = fminf(r2[t], r2[t + s]); } __syncthreads(); }
    float cmax = r1[0], cmin = r2[0];
    __syncthreads();
    if (t == 0) {
        float var  = fmaxf(cms - cm * cm, 0.0f);
        float cstd = sqrtf(var);
        zs[0] = cm; zs[1] = cmax; zs[2] = cmin; zs[3] = cstd;
        float w = 0.15f + 1e-6f;
        for (int k = 0; k < 8; ++k) {
            float ck = (float)k / 7.0f;
            float d1 = (cm   - ck) / w;
            float d2 = (cmax - ck) / w;
            zs[4 + k]  = expf(-0.5f * d1 * d1);
            zs[12 + k] = expf(-0.5f * d2 * d2);
        }
    }
    __syncthreads();
    float pl = peb[t];
    #pragma unroll
    for (int f = 0; f < 20; ++f) pl += zs[f] * peW[t * 20 + f];
    r1[t] = pl; r2[t] = pl * pl;
    __syncthreads();
    for (int s = 128; s > 0; s >>= 1) { if (t < s) { r1[t] += r1[t + s]; r2[t] += r2[t + s]; } __syncthreads(); }
    float m  = r1[0] * (1.0f / 256.0f);
    float vv = fmaxf(r2[0] * (1.0f / 256.0f) - m * m, 0.0f);
    float pe = (pl - m) * rsqrtf(vv + 1e-5f) * peg[t] + pebt[t];
    pe *= gate[0];
    if (mask[i] != 0) pe = 0.0f;
    float hv = bp[t];
    #pragma unroll
    for (int k = 0; k < DIN; ++k) hv += xs[k] * Wp[t * DIN + k];
    float o = hv + pe;
    h[(size_t)i * 256 + t] = o;
    hb[(size_t)i * 256 + t] = f2b_rne(o);
}

// ---------------- wave-per-row LN body ----------------
static __device__ __forceinline__ void ln_row(const float* in, const float* g, const float* b,
                                              unsigned short* out, int row, int lane) {
    float4 v = *(const float4*)(in + (size_t)row * 256 + lane * 4);
    float s  = v.x + v.y + v.z + v.w;
    float s2 = v.x * v.x + v.y * v.y + v.z * v.z + v.w * v.w;
    #pragma unroll
    for (int o = 32; o > 0; o >>= 1) { s += __shfl_xor(s, o); s2 += __shfl_xor(s2, o); }
    float m  = s * (1.0f / 256.0f);
    float vv = fmaxf(s2 * (1.0f / 256.0f) - m * m, 0.0f);
    float rs = rsqrtf(vv + 1e-5f);
    float4 gg = *(const float4*)(g + lane * 4);
    float4 bb = *(const float4*)(b + lane * 4);
    uint2 o2;
    o2.x = pack_b16((v.x - m) * rs * gg.x + bb.x, (v.y - m) * rs * gg.y + bb.y);
    o2.y = pack_b16((v.z - m) * rs * gg.z + bb.z, (v.w - m) * rs * gg.w + bb.w);
    *(uint2*)(out + (size_t)row * 256 + lane * 4) = o2;
}

__global__ __launch_bounds__(256) void ln_b16_w_kernel(const float* __restrict__ in, const float* __restrict__ g,
                                                       const float* __restrict__ b, unsigned short* __restrict__ out) {
    int w = threadIdx.x >> 6, lane = threadIdx.x & 63;
    ln_row(in, g, b, out, blockIdx.x * 4 + w, lane);
}

__global__ __launch_bounds__(256) void ln_dual_kernel(const float* __restrict__ in0, const float* __restrict__ g0,
                                                      const float* __restrict__ b0, unsigned short* __restrict__ out0, int n0,
                                                      const float* __restrict__ in1, const float* __restrict__ g1,
                                                      const float* __restrict__ b1, unsigned short* __restrict__ out1) {
    int w = threadIdx.x >> 6, lane = threadIdx.x & 63;
    int row = blockIdx.x * 4 + w;
    bool first = row < n0;
    const float* in = first ? in0 : in1;
    const float* g  = first ? g0  : g1;
    const float* b  = first ? b0  : b1;
    unsigned short* out = first ? out0 : out1;
    ln_row(in, g, b, out, first ? row : row - n0, lane);
}

__global__ __launch_bounds__(256) void ln_out_w_kernel(const float* __restrict__ in, const float* __restrict__ g,
                                                       const float* __restrict__ b, float* __restrict__ out) {
    int w = threadIdx.x >> 6, lane = threadIdx.x & 63;
    int row = blockIdx.x * 4 + w;
    float4 v = *(const float4*)(in + (size_t)row * 256 + lane * 4);
    float s  = v.x + v.y + v.z + v.w;
    float s2 = v.x * v.x + v.y * v.y + v.z * v.z + v.w * v.w;
    #pragma unroll
    for (int o = 32; o > 0; o >>= 1) { s += __shfl_xor(s, o); s2 += __shfl_xor(s2, o); }
    float m  = s * (1.0f / 256.0f);
    float vv = fmaxf(s2 * (1.0f / 256.0f) - m * m, 0.0f);
    float rs = rsqrtf(vv + 1e-5f);
    float4 gg = *(const float4*)(g + lane * 4);
    float4 bb = *(const float4*)(b + lane * 4);
    float4 o4;
    o4.x = (v.x - m) * rs * gg.x + bb.x;
    o4.y = (v.y - m) * rs * gg.y + bb.y;
    o4.z = (v.z - m) * rs * gg.z + bb.z;
    o4.w = (v.w - m) * rs * gg.w + bb.w;
    *(float4*)(out + (size_t)row * 256 + lane * 4) = o4;
}

// ---------------- multi-job MFMA GEMM (64x64 tile, 4 waves) ----------------
struct GJob {
    const unsigned short* A; const int* ridx; const unsigned short* W;
    const float* bias; const float* res; const float* scale;
    void* out; void* out2; void* vtf;
    int lda, ldw, ldo, omode, kbase, K, act, gx;
    float scmul;
};

static __device__ __forceinline__ void gemm_body(const GJob& j, int bx, int by) {
    __shared__ unsigned short As[64][72];
    __shared__ unsigned short Ws[64][72];
    int tid = threadIdx.x;
    int lane = tid & 63, wid = tid >> 6;
    int c15 = lane & 15, g = lane >> 4;
    int wm = wid & 1, wn = wid >> 1;
    int row0 = by * 64, col0 = bx * 64;
    f32x4 acc[2][2];
    const f32x4 zf = {0.f, 0.f, 0.f, 0.f};
    acc[0][0] = zf; acc[0][1] = zf; acc[1][0] = zf; acc[1][1] = zf;

    for (int k0 = 0; k0 < j.K; k0 += 64) {
        #pragma unroll
        for (int hh = 0; hh < 2; ++hh) {
            int cid = tid + hh * 256;
            int rr = cid >> 3, cc = (cid & 7) * 8;
            int arow = j.ridx ? j.ridx[row0 + rr] : (row0 + rr);
            short8v va = *(const short8v*)(j.A + (size_t)arow * j.lda + k0 + cc);
            short8v vw = *(const short8v*)(j.W + (size_t)(col0 + rr) * j.ldw + k0 + cc);
            *(short8v*)(&As[rr][cc]) = va;
            *(short8v*)(&Ws[rr][cc]) = vw;
        }
        __syncthreads();
        #pragma unroll
        for (int ks = 0; ks < 2; ++ks) {
            short8v a0 = *(const short8v*)(&As[wm * 32 + c15][ks * 32 + g * 8]);
            short8v a1 = *(const short8v*)(&As[wm * 32 + 16 + c15][ks * 32 + g * 8]);
            short8v w0 = *(const short8v*)(&Ws[wn * 32 + c15][ks * 32 + g * 8]);
            short8v w1 = *(const short8v*)(&Ws[wn * 32 + 16 + c15][ks * 32 + g * 8]);
            acc[0][0] = __builtin_amdgcn_mfma_f32_16x16x32_bf16(a0, w0, acc[0][0], 0, 0, 0);
            acc[0][1] = __builtin_amdgcn_mfma_f32_16x16x32_bf16(a0, w1, acc[0][1], 0, 0, 0);
            acc[1][0] = __builtin_amdgcn_mfma_f32_16x16x32_bf16(a1, w0, acc[1][0], 0, 0, 0);
            acc[1][1] = __builtin_amdgcn_mfma_f32_16x16x32_bf16(a1, w1, acc[1][1], 0, 0, 0);
        }
        __syncthreads();
    }
    float sc = (j.scale ? *j.scale : 1.0f) * j.scmul;
    #pragma unroll
    for (int nf = 0; nf < 2; ++nf) {
        int n = col0 + wn * 32 + nf * 16 + c15;
        float bv = j.bias ? j.bias[n] : 0.0f;
        #pragma unroll
        for (int mf = 0; mf < 2; ++mf) {
            #pragma unroll
            for (int r = 0; r < 4; ++r) {
                int m = row0 + wm * 32 + mf * 16 + g * 4 + r;
                float v = acc[mf][nf][r] * sc + bv;
                if (j.act) v = gelu_exact(v);
                if (j.res) v += j.res[(size_t)m * j.ldo + n];
                if (j.omode == 0) {
                    ((float*)j.out)[(size_t)m * j.ldo + n] = v;
                    if (j.out2) ((unsigned short*)j.out2)[(size_t)m * j.ldo + n] = f2b_rne(v);
                } else if (j.omode == 1) {
                    ((unsigned short*)j.out)[(size_t)m * j.ldo + n] = f2b_rne(v);
                } else if (j.omode == 2) {
                    ((unsigned short*)j.out)[bswz_idx(m, n)] = f2b_rne(v);
                } else {
                    unsigned short bw = f2b_rne(v);
                    int nk = n - j.kbase;
                    if (nk < 0) {
                        ((unsigned short*)j.out)[(size_t)m * j.ldo + n] = bw;
                    } else if (nk < 256) {
                        ((unsigned short*)j.out2)[kfrag_idx(nk >> 5, m, nk & 31)] = bw;
                    } else {
                        ((unsigned short*)j.vtf)[vtfrag_idx((nk - 256) >> 5, m, (nk - 256) & 31)] = bw;
                    }
                }
            }
        }
    }
}

__global__ __launch_bounds__(256) void gemm_multi_kernel(GJob j0, GJob j1, GJob j2, int e0, int e1) {
    int b = blockIdx.x;
    GJob j;
    int bb;
    if (b < e0)      { j = j0; bb = b; }
    else if (b < e1) { j = j1; bb = b - e0; }
    else             { j = j2; bb = b - e1; }
    gemm_body(j, bb % j.gx, bb / j.gx);
}

// ---------------- transpose-swz body ----------------
static __device__ __forceinline__ void transpose_body(const float* C, const float* beta,
                                                      const float* maskadd, unsigned short* CTswz,
                                                      int bxi, int byi) {
    __shared__ float tile[32][33];
    int bx = bxi * 32;
    int by = byi * 32;
    int tx = threadIdx.x & 31, ty = threadIdx.x >> 5;
    float bt = beta[0] * LOG2E;
    #pragma unroll
    for (int r = 0; r < 4; ++r) {
        int row = bx + ty + r * 8;
        tile[ty + r * 8][tx] = C[(size_t)row * 256 + by + tx];
    }
    __syncthreads();
    #pragma unroll
    for (int r = 0; r < 4; ++r) {
        int srow = by + ty + r * 8;
        int col  = bx + tx;
        CTswz[bswz_idx(srow, col)] = f2b_rne(bt * tile[tx][ty + r * 8] + maskadd[col]);
    }
}

__global__ __launch_bounds__(256) void mega0_kernel(
    const float* __restrict__ C, const float* __restrict__ beta,
    const float* __restrict__ maskadd, unsigned short* __restrict__ CTswz,
    GJob j0, GJob j1, int ntr, int e0)
{
    int b = blockIdx.x;
    if (b < ntr) { transpose_body(C, beta, maskadd, CTswz, b % 96, b / 96); return; }
    b -= ntr;
    GJob j;
    int bb;
    if (b < e0) { j = j0; bb = b; }
    else        { j = j1; bb = b - e0; }
    gemm_body(j, bb % j.gx, bb / j.gx);
}

// ---------------- split-K MFMA flash attention (body) ----------------
template<int SPLIT>
static __device__ __forceinline__ void attn_body(
    const unsigned short* __restrict__ Qb, int ldq,
    const unsigned short* __restrict__ Kfrag,
    const unsigned short* __restrict__ VTfrag,
    const unsigned short* __restrict__ biasswz,
    unsigned short* __restrict__ out, int qx)
{
    constexpr int KT = 48 / SPLIT;
    __shared__ unsigned short P_all[SPLIT * 32 * 72];
    __shared__ float ml[SPLIT * 64];
    const int head = blockIdx.y;
    const int i0 = qx * 32;
    const int qt0 = qx * 2;
    const int tid = threadIdx.x;
    const int lane = tid & 63, w = tid >> 6;
    const int c15 = lane & 15, g = lane >> 4;
    unsigned short* P_lds = P_all + w * (32 * 72);
    const unsigned short* Kf  = Kfrag  + (size_t)head * 192 * 512;
    const unsigned short* VTf = VTfrag + (size_t)head * 48 * 2048;
    const f32x4 zf = {0.f, 0.f, 0.f, 0.f};
    const float rsl2 = 0.25503164113124427f;

    short8v qf[2];
    #pragma unroll
    for (int nf = 0; nf < 2; ++nf)
        qf[nf] = *(const short8v*)(Qb + (size_t)(i0 + nf * 16 + c15) * ldq + head * 32 + g * 8);

    float m_[2] = {-1e30f, -1e30f};
    float l_[2] = {0.f, 0.f};
    f32x4 acc[2][2];
    acc[0][0] = zf; acc[0][1] = zf; acc[1][0] = zf; acc[1][1] = zf;

    for (int kt = 0; kt < KT; ++kt) {
        const int k0 = (w * KT + kt) * 64;
        const int kt16 = k0 >> 4;
        short8v kf[4];
        #pragma unroll
        for (int mf = 0; mf < 4; ++mf)
            kf[mf] = *(const short8v*)(Kf + ((size_t)(kt16 + mf) * 64 + lane) * 8);
        f32x4 s[4][2];
        __builtin_amdgcn_s_setprio(1);
        #pragma unroll
        for (int mf = 0; mf < 4; ++mf)
            #pragma unroll
            for (int nf = 0; nf < 2; ++nf)
                s[mf][nf] = __builtin_amdgcn_mfma_f32_16x16x32_bf16(kf[mf], qf[nf], zf, 0, 0, 0);
        __builtin_amdgcn_s_setprio(0);
        #pragma unroll
        for (int nf = 0; nf < 2; ++nf) {
            const unsigned short* bb = biasswz + ((size_t)(qt0 + nf) * 192 + kt16) * 256 + lane * 4;
            #pragma unroll
            for (int mf = 0; mf < 4; ++mf) {
                uint2 bv = *(const uint2*)(bb + mf * 256);
                s[mf][nf][0] = s[mf][nf][0] * rsl2 + __uint_as_float(bv.x << 16);
                s[mf][nf][1] = s[mf][nf][1] * rsl2 + __uint_as_float(bv.x & 0xffff0000u);
                s[mf][nf][2] = s[mf][nf][2] * rsl2 + __uint_as_float(bv.y << 16);
                s[mf][nf][3] = s[mf][nf][3] * rsl2 + __uint_as_float(bv.y & 0xffff0000u);
            }
        }
        #pragma unroll
        for (int nf = 0; nf < 2; ++nf) {
            float t0 = fmaxf(fmaxf(s[0][nf][0], s[0][nf][1]), fmaxf(s[0][nf][2], s[0][nf][3]));
            float t1 = fmaxf(fmaxf(s[1][nf][0], s[1][nf][1]), fmaxf(s[1][nf][2], s[1][nf][3]));
            float t2 = fmaxf(fmaxf(s[2][nf][0], s[2][nf][1]), fmaxf(s[2][nf][2], s[2][nf][3]));
            float t3 = fmaxf(fmaxf(s[3][nf][0], s[3][nf][1]), fmaxf(s[3][nf][2], s[3][nf][3]));
            float tmax = fmaxf(fmaxf(t0, t1), fmaxf(t2, t3));
            tmax = fmaxf(tmax, __shfl_xor(tmax, 16));
            tmax = fmaxf(tmax, __shfl_xor(tmax, 32));
            if (!__all(tmax <= m_[nf] + 8.0f)) {
                float mn = fmaxf(m_[nf], tmax);
                float scl = EXP2(m_[nf] - mn);
                m_[nf] = mn;
                l_[nf] *= scl;
                #pragma unroll
                for (int mf = 0; mf < 2; ++mf) {
                    acc[mf][nf][0] *= scl; acc[mf][nf][1] *= scl;
                    acc[mf][nf][2] *= scl; acc[mf][nf][3] *= scl;
                }
            }
            float mcur = m_[nf];
            float ps0 = 0.f, ps1 = 0.f, ps2 = 0.f, ps3 = 0.f;
            #pragma unroll
            for (int mf = 0; mf < 4; ++mf) {
                float p0 = EXP2(s[mf][nf][0] - mcur);
                float p1 = EXP2(s[mf][nf][1] - mcur);
                float p2 = EXP2(s[mf][nf][2] - mcur);
                float p3 = EXP2(s[mf][nf][3] - mcur);
                s[mf][nf][0] = p0; s[mf][nf][1] = p1;
                s[mf][nf][2] = p2; s[mf][nf][3] = p3;
                ps0 += p0; ps1 += p1; ps2 += p2; ps3 += p3;
            }
            l_[nf] += (ps0 + ps1) + (ps2 + ps3);
            const int q = nf * 16 + c15;
            #pragma unroll
            for (int mf = 0; mf < 4; ++mf) {
                uint2 pv;
                pv.x = pack_b16(s[mf][nf][0], s[mf][nf][1]);
                pv.y = pack_b16(s[mf][nf][2], s[mf][nf][3]);
                *(uint2*)(P_lds + q * 72 + mf * 16 + g * 4) = pv;
            }
        }
        const unsigned short* vb = VTf + (size_t)(k0 >> 6) * 2048;
        #pragma unroll
        for (int ks = 0; ks < 2; ++ks) {
            short8v pB[2], vA[2];
            #pragma unroll
            for (int nf = 0; nf < 2; ++nf)
                pB[nf] = *(const short8v*)(P_lds + (nf * 16 + c15) * 72 + ks * 32 + g * 8);
            #pragma unroll
            for (int mf = 0; mf < 2; ++mf)
                vA[mf] = *(const short8v*)(vb + ((size_t)(ks * 2 + mf) * 64 + lane) * 8);
            __builtin_amdgcn_s_setprio(1);
            #pragma unroll
            for (int mf = 0; mf < 2; ++mf)
                #pragma unroll
                for (int nf = 0; nf < 2; ++nf)
                    acc[mf][nf] = __builtin_amdgcn_mfma_f32_16x16x32_bf16(vA[mf], pB[nf], acc[mf][nf], 0, 0, 0);
            __builtin_amdgcn_s_setprio(0);
        }
    }

    float* Olds = (float*)P_all;
    #pragma unroll
    for (int nf = 0; nf < 2; ++nf) {
        float lv = l_[nf];
        lv += __shfl_xor(lv, 16);
        lv += __shfl_xor(lv, 32);
        int q = nf * 16 + c15;
        #pragma unroll
        for (int mf = 0; mf < 2; ++mf)
            *(f32x4*)(Olds + w * 1152 + q * 36 + mf * 16 + g * 4) = acc[mf][nf];
        if (g == 0) {
            ml[w * 64 + q] = m_[nf];
            ml[w * 64 + 32 + q] = lv;
        }
    }
    __syncthreads();
    if (tid < 256) {
        int q = tid >> 3, d0 = (tid & 7) * 4;
        float M = -1e30f;
        #pragma unroll
        for (int s = 0; s < SPLIT; ++s) M = fmaxf(M, ml[s * 64 + q]);
        float L = 0.f;
        float v0 = 0, v1 = 0, v2 = 0, v3 = 0;
        #pragma unroll
        for (int s = 0; s < SPLIT; ++s) {
            float wv = EXP2(ml[s * 64 + q] - M);
            L += wv * ml[s * 64 + 32 + q];
            const float* op = Olds + s * 1152 + q * 36 + d0;
            v0 += wv * op[0]; v1 += wv * op[1];
            v2 += wv * op[2]; v3 += wv * op[3];
        }
        float invL = 1.0f / L;
        uint2 pk;
        pk.x = pack_b16(v0 * invL, v1 * invL);
        pk.y = pack_b16(v2 * invL, v3 * invL);
        *(uint2*)(out + (size_t)(i0 + q) * 256 + head * 32 + d0) = pk;
    }
}

template<int SPLIT>
__global__ __launch_bounds__(64 * SPLIT) void attn_multi_kernel(
    const unsigned short* Q0, const unsigned short* K0, const unsigned short* V0,
    const unsigned short* B0, unsigned short* O0, int nx0,
    const unsigned short* Q1, const unsigned short* K1, const unsigned short* V1,
    const unsigned short* B1, unsigned short* O1)
{
    int bx = blockIdx.x;
    bool first = bx < nx0;
    const unsigned short* Q = first ? Q0 : Q1;
    const unsigned short* K = first ? K0 : K1;
    const unsigned short* V = first ? V0 : V1;
    const unsigned short* B = first ? B0 : B1;
    unsigned short* O = first ? O0 : O1;
    attn_body<SPLIT>(Q, 256, K, V, B, O, first ? bx : bx - nx0);
}

extern "C" void kernel_launch(void* const* d_in, const int* in_sizes, int n_in,
                              void* d_out, int out_size, void* d_ws, size_t ws_size,
                              hipStream_t stream)
{
    const float* x        = (const float*)d_in[0];
    const float* C        = (const float*)d_in[1];
    const int*   sidx     = (const int*)d_in[2];
    const unsigned char* mask = (const unsigned char*)d_in[3];
    const float* proj_W   = (const float*)d_in[4];
    const float* proj_b   = (const float*)d_in[5];
    const float* peW      = (const float*)d_in[6];
    const float* peb      = (const float*)d_in[7];
    const float* peg      = (const float*)d_in[8];
    const float* pebt     = (const float*)d_in[9];
    const float* pe_gate  = (const float*)d_in[10];
    const float* alpha_nn = (const float*)d_in[11];
    const float* beta_sn  = (const float*)d_in[12];
    const float* sqW      = (const float*)d_in[13];
    const float* sqb      = (const float*)d_in[14];
    const float* sn_Win   = (const float*)d_in[15];
    const float* sn_bin   = (const float*)d_in[16];
    const float* sn_Wout  = (const float*)d_in[17];
    const float* sn_bout  = (const float*)d_in[18];
    const float* nn_Win   = (const float*)d_in[19];
    const float* nn_bin   = (const float*)d_in[20];
    const float* nn_Wout  = (const float*)d_in[21];
    const float* nn_bout  = (const float*)d_in[22];
    const float* ln_s_g   = (const float*)d_in[23];
    const float* ln_s_b   = (const float*)d_in[24];
    const float* ln_n1_g  = (const float*)d_in[25];
    const float* ln_n1_b  = (const float*)d_in[26];
    const float* ln_n2_g  = (const float*)d_in[27];
    const float* ln_n2_b  = (const float*)d_in[28];
    const float* ffn_W1   = (const float*)d_in[29];
    const float* ffn_b1   = (const float*)d_in[30];
    const float* ffn_W2   = (const float*)d_in[31];
    const float* ffn_b2   = (const float*)d_in[32];
    const float* ffs_W1   = (const float*)d_in[33];
    const float* ffs_b1   = (const float*)d_in[34];
    const float* ffs_W2   = (const float*)d_in[35];
    const float* ffs_b2   = (const float*)d_in[36];
    const float* ln_og    = (const float*)d_in[37];
    const float* ln_ob    = (const float*)d_in[38];

    float* ws = (float*)d_ws;
    float* h       = ws;                                          // 786432 f
    float* sinkq   = ws + 786432;                                 // 65536
    float* maskadd = ws + 851968;                                 // 4096
    unsigned short* Cnb     = (unsigned short*)(ws + 856064);     // 393216 f
    unsigned short* hb      = (unsigned short*)(ws + 1249280);    // 393216 f
    unsigned short* hnb     = (unsigned short*)(ws + 1642496);    // 393216 f
    unsigned short* attnob_n= (unsigned short*)(ws + 2035712);    // 393216 f
    unsigned short* attnob_s= (unsigned short*)(ws + 2428928);    // 32768 f
    unsigned short* sqnb    = (unsigned short*)(ws + 2461696);    // 32768 f
    unsigned short* sinkqb  = (unsigned short*)(ws + 2494464);    // 32768 f
    unsigned short* Kfrag_n = (unsigned short*)(ws + 2527232);    // 393216 f
    unsigned short* VTfrag_n= (unsigned short*)(ws + 2920448);    // 393216 f
    unsigned short* Kfrag_s = (unsigned short*)(ws + 3313664);    // 393216 f
    unsigned short* VTfrag_s= (unsigned short*)(ws + 3706880);    // 393216 f
    unsigned short* CTswz   = (unsigned short*)(ws + 4100096);    // 393216 f
    unsigned short* biasswz = (unsigned short*)(ws + 4493312);    // 4718592 f
    unsigned short* wb      = (unsigned short*)(ws + 9211904);    // 2392064 f
    float* big      = ws + 11603968;                              // 1966080 f -> ends 13570048
    unsigned short* sqWb    = wb;
    unsigned short* snWinb  = wb + 65536;
    unsigned short* snWoutb = wb + 655360;
    unsigned short* nnWinb  = wb + 851968;
    unsigned short* nnWoutb = wb + 1441792;
    unsigned short* ffnW1b  = wb + 1638400;
    unsigned short* ffnW2b  = wb + 2424832;
    unsigned short* ffsW1b  = wb + 3211264;
    unsigned short* ffsW2b  = wb + 3997696;
    unsigned short* q_sb  = (unsigned short*)big;                 // 256x256
    unsigned short* mid_sb= (unsigned short*)big + 65536;         // 256x1024
    unsigned short* Qnb   = (unsigned short*)big + 327680;        // 3072x256
    unsigned short* midb  = (unsigned short*)big + 1114112;       // 3072x1024

    dim3 b256(256), b512(512);
    GJob jz = {};  jz.gx = 1;

    CvtJobs cj;
    cj.src[0] = sqW;     cj.dst[0] = sqWb;    cj.cnt4[0] = 16384;
    cj.src[1] = sn_Win;  cj.dst[1] = snWinb;  cj.cnt4[1] = 147456;
    cj.src[2] = sn_Wout; cj.dst[2] = snWoutb; cj.cnt4[2] = 49152;
    cj.src[3] = nn_Win;  cj.dst[3] = nnWinb;  cj.cnt4[3] = 147456;
    cj.src[4] = nn_Wout; cj.dst[4] = nnWoutb; cj.cnt4[4] = 49152;
    cj.src[5] = ffn_W1;  cj.dst[5] = ffnW1b;  cj.cnt4[5] = 196608;
    cj.src[6] = ffn_W2;  cj.dst[6] = ffnW2b;  cj.cnt4[6] = 196608;
    cj.src[7] = ffs_W1;  cj.dst[7] = ffsW1b;  cj.cnt4[7] = 196608;
    cj.src[8] = ffs_W2;  cj.dst[8] = ffsW2b;  cj.cnt4[8] = 196608;

    prep_misc_kernel<<<4672 + 12 + 768, b256, 0, stream>>>(cj, 1196032, 4672, mask, maskadd, C, Cnb);
    node_encode_kernel<<<N_NODES, b256, 0, stream>>>(x, C, mask, proj_W, proj_b, peW, peb, peg, pebt, pe_gate, h, hb);
    {
        GJob j0 = {hb, sidx, sqWb, sqb, nullptr, nullptr, sinkq, nullptr, nullptr, 256, 256, 256, 0, 0, 256, 0, 4, 1.0f};
        GJob j1 = {Cnb, nullptr, Cnb, maskadd, nullptr, alpha_nn, biasswz, nullptr, nullptr, 256, 256, 3072, 2, 0, 256, 0, 48, LOG2E};
        mega0_kernel<<<768 + 16 + 2304, b256, 0, stream>>>(C, beta_sn, maskadd, CTswz, j0, j1, 768, 16);
    }

    for (int l = 0; l < 3; ++l) {
        const float* lsg = ln_s_g + l * 256,  *lsb = ln_s_b + l * 256;
        const float* l1g = ln_n1_g + l * 256, *l1b = ln_n1_b + l * 256;
        ln_dual_kernel<<<832, b256, 0, stream>>>(sinkq, lsg, lsb, sqnb, 256, h, l1g, l1b, hnb);
        {
            GJob j0 = {sqnb, nullptr, snWinb + (size_t)l * 196608, sn_bin + l * 768, nullptr, nullptr, q_sb, nullptr, nullptr, 256, 256, 256, 1, 0, 256, 0, 4, 1.0f};
            GJob j1 = {hb, nullptr, snWinb + (size_t)l * 196608 + 65536, sn_bin + l * 768 + 256, nullptr, nullptr, nullptr, Kfrag_s, VTfrag_s, 256, 256, 0, 3, 0, 256, 0, 8, 1.0f};
            GJob j2 = {hnb, nullptr, nnWinb + (size_t)l * 196608, nn_bin + l * 768, nullptr, nullptr, Qnb, Kfrag_n, VTfrag_n, 256, 256, 256, 3, 256, 256, 0, 12, 1.0f};
            gemm_multi_kernel<<<16 + 384 + 576, b256, 0, stream>>>(j0, j1, j2, 16, 16 + 384);
        }
        attn_multi_kernel<8><<<dim3(8 + 96, 8), b512, 0, stream>>>(
            q_sb, Kfrag_s, VTfrag_s, CTswz, attnob_s, 8,
            Qnb, Kfrag_n, VTfrag_n, biasswz, attnob_n);
        {
            GJob j0 = {attnob_s, nullptr, snWoutb + (size_t)l * 65536, sn_bout + l * 256, sinkq, nullptr, sinkq, sinkqb, nullptr, 256, 256, 256, 0, 0, 256, 0, 4, 1.0f};
            GJob j1 = {attnob_n, nullptr, nnWoutb + (size_t)l * 65536, nn_bout + l * 256, h, nullptr, h, nullptr, nullptr, 256, 256, 256, 0, 0, 256, 0, 4, 1.0f};
            gemm_multi_kernel<<<16 + 192, b256, 0, stream>>>(j0, j1, jz, 16, 16 + 192);
        }
        ln_b16_w_kernel<<<768, b256, 0, stream>>>(h, ln_n2_g + l * 256, ln_n2_b + l * 256, hnb);
        {
            GJob j0 = {sinkqb, nullptr, ffsW1b + (size_t)l * 262144, ffs_b1 + l * 1024, nullptr, nullptr, mid_sb, nullptr, nullptr, 256, 256, 1024, 1, 0, 256, 1, 16, 1.0f};
            GJob j1 = {hnb, nullptr, ffnW1b + (size_t)l * 262144, ffn_b1 + l * 1024, nullptr, nullptr, midb, nullptr, nullptr, 256, 256, 1024, 1, 0, 256, 1, 16, 1.0f};
            gemm_multi_kernel<<<64 + 768, b256, 0, stream>>>(j0, j1, jz, 64, 64 + 768);
        }
        {
            GJob j0 = {mid_sb, nullptr, ffsW2b + (size_t)l * 262144, ffs_b2 + l * 256, sinkq, nullptr, sinkq, nullptr, nullptr, 1024, 1024, 256, 0, 0, 1024, 0, 4, 1.0f};
            GJob j1 = {midb, nullptr, ffnW2b + (size_t)l * 262144, ffn_b2 + l * 256, h, nullptr, h, hb, nullptr, 1024, 1024, 256, 0, 0, 1024, 0, 4, 1.0f};
            gemm_multi_kernel<<<16 + 192, b256, 0, stream>>>(j0, j1, jz, 16, 16 + 192);
        }
    }

    ln_out_w_kernel<<<64, b256, 0, stream>>>(sinkq, ln_og, ln_ob, (float*)d_out);
}